// Round 4
// baseline (388.462 us; speedup 1.0000x reference)
//
#include <hip/hip_runtime.h>

#define NG    32768
#define NN    128
#define NE    1024
#define NK    32
#define NB    (NG / 2)
#define RSTR  17                 // A row stride in dwords (odd -> conflict-free)
#define AWDW  (NN * RSTR)        // 2176 dwords per graph table (8.5 KB)

// R8b: identical to R8 (bench infra failed before execution; resubmit).
// Occupancy-doubling restructure. Two waves share ONE graph's A-table
// (each scatters half the edges; each lane owns ONE dst row). LDS/block
// drops 34.8KB -> 17.4KB => 8 blocks/CU = 32 waves/CU (was 4 blocks = 16).
// Per-graph VALU work is conserved (same dense unpack+MAC, spread over 2
// waves); the win is latency hiding at 8 waves/SIMD. Block handles one
// output pair: waves {0,1} -> graph b, waves {2,3} -> graph b+NB.
__global__ __launch_bounds__(256, 8) void dcnn_adj_kernel(
    const float* __restrict__ x,      // (G, N, 3)
    const int*   __restrict__ esrc,   // (G, E)
    const int*   __restrict__ edst,   // (G, E)
    const float* __restrict__ extx,   // (G, K, 3)
    const float* __restrict__ W,      // (3,3)
    const float* __restrict__ M,      // (3,3)
    const float* __restrict__ U,      // (3,3)
    const float* __restrict__ V,      // (3,3)
    const float* __restrict__ W1,     // (6,3)
    const float* __restrict__ b1,     // (3,)
    const float* __restrict__ W2,     // (3,2)
    const float* __restrict__ b2,     // (2,)
    float* __restrict__ out)          // (B, 2)
{
    __shared__ unsigned A[2 * AWDW];  // 17.4 KB: one table per graph slot
    __shared__ float pw[4][6];        // per-wave partials {h0,h1,h2,e0,e1,e2}
    __shared__ float ge[2][3];        // per-graph g_emb

    const int t     = threadIdx.x;
    const int w     = t >> 6;
    const int lane  = t & 63;
    const int half  = w & 1;          // which half of this graph's work
    const int gslot = w >> 1;         // 0: graph `pair`, 1: graph `pair+NB`
    const int pair  = blockIdx.x;
    const int g     = gslot ? (pair + NB) : pair;

    // wave-uniform graph id in SGPR -> dense-loop x reads become s_load
    const int gu = __builtin_amdgcn_readfirstlane(g);
    const float* __restrict__ xg = x + (size_t)gu * (NN * 3);

    // ---- edge lists: 8 edges/lane (this wave's half of 1024) --------------
    const int4* sp = (const int4*)(esrc + (size_t)gu * NE);
    const int4* dp = (const int4*)(edst + (size_t)gu * NE);
    const int ebase = half * 128 + lane;
    const int4 s0 = sp[ebase], s1 = sp[ebase + 64];
    const int4 d0 = dp[ebase], d1 = dp[ebase + 64];

    // ext row (half-0 wave, lanes 0..31)
    float er0 = 0.f, er1 = 0.f, er2 = 0.f;
    if (half == 0 && lane < NK) {
        const float* ep = extx + (size_t)gu * (NK * 3) + lane * 3;
        er0 = ep[0]; er1 = ep[1]; er2 = ep[2];
    }

    // ---- zero both tables cooperatively: 4352 dwords / 256 threads --------
    #pragma unroll
    for (int i = 0; i < 17; ++i) A[i * 256 + t] = 0u;
    __syncthreads();

    // ---- build adjacency counts: ONE no-return ds_add_u32 per edge --------
    unsigned* Aw = &A[gslot * AWDW];
    #define SCAT(SV, DV)                                                    \
        {                                                                   \
            const unsigned off = (unsigned)(size_t)&Aw[(DV) * RSTR + ((SV) >> 3)]; \
            const unsigned val = 1u << (4 * ((SV) & 7));                    \
            asm volatile("ds_add_u32 %0, %1" :: "v"(off), "v"(val) : "memory"); \
        }
    SCAT(s0.x, d0.x) SCAT(s0.y, d0.y) SCAT(s0.z, d0.z) SCAT(s0.w, d0.w)
    SCAT(s1.x, d1.x) SCAT(s1.y, d1.y) SCAT(s1.z, d1.z) SCAT(s1.w, d1.w)
    #undef SCAT

    // each wave drains its own (asm-hidden) atomics before the barrier;
    // after the barrier both waves' scatters are complete.
    asm volatile("s_waitcnt lgkmcnt(0)" ::: "memory");
    __syncthreads();

    // ---- agg = A @ x : lane owns dst row (half*64 + lane), agg in regs ----
    const int row = half * 64 + lane;
    const int r0  = row * RSTR;
    float ac0 = 0.f, ac1 = 0.f, ac2 = 0.f;

    #pragma unroll
    for (int j = 0; j < 16; ++j) {
        const unsigned da = Aw[r0 + j];
        // x for srcs j*8 .. j*8+7 : wave-uniform address -> s_load (SGPRs)
        float q[24];
        *(float4*)&q[0]  = *(const float4*)(xg + j * 24);
        *(float4*)&q[4]  = *(const float4*)(xg + j * 24 + 4);
        *(float4*)&q[8]  = *(const float4*)(xg + j * 24 + 8);
        *(float4*)&q[12] = *(const float4*)(xg + j * 24 + 12);
        *(float4*)&q[16] = *(const float4*)(xg + j * 24 + 16);
        *(float4*)&q[20] = *(const float4*)(xg + j * 24 + 20);
        #pragma unroll
        for (int o = 0; o < 8; ++o) {
            const float ca = (float)((da >> (4 * o)) & 15u);
            ac0 += ca * q[o * 3];
            ac1 += ca * q[o * 3 + 1];
            ac2 += ca * q[o * 3 + 2];
        }
    }

    // ---- h = relu(xW + aggM) for the owned node ---------------------------
    float h0, h1, h2;
    {
        const float* xr = xg + row * 3;
        const float x0 = xr[0], x1 = xr[1], x2 = xr[2];
        h0 = fmaxf(x0 * W[0] + x1 * W[3] + x2 * W[6] +
                   ac0 * M[0] + ac1 * M[3] + ac2 * M[6], 0.f);
        h1 = fmaxf(x0 * W[1] + x1 * W[4] + x2 * W[7] +
                   ac0 * M[1] + ac1 * M[4] + ac2 * M[7], 0.f);
        h2 = fmaxf(x0 * W[2] + x1 * W[5] + x2 * W[8] +
                   ac0 * M[2] + ac1 * M[5] + ac2 * M[8], 0.f);
    }

    // ---- reduce within 32-lane halves, combine halves via readlane --------
    #pragma unroll
    for (int off = 16; off > 0; off >>= 1) {
        h0  += __shfl_xor(h0,  off);
        h1  += __shfl_xor(h1,  off);
        h2  += __shfl_xor(h2,  off);
        er0 += __shfl_xor(er0, off);
        er1 += __shfl_xor(er1, off);
        er2 += __shfl_xor(er2, off);
    }
    #define RL(v) (__uint_as_float(__builtin_amdgcn_readlane(__float_as_uint(v), 0)) + \
                   __uint_as_float(__builtin_amdgcn_readlane(__float_as_uint(v), 32)))
    if (lane == 0) {
        pw[w][0] = RL(h0);  pw[w][1] = RL(h1);  pw[w][2] = RL(h2);
        pw[w][3] = RL(er0); pw[w][4] = RL(er1); pw[w][5] = RL(er2);
    }
    #undef RL

    __syncthreads();

    // ---- per-graph tail on lane 0 of waves 0 and 2 ------------------------
    if (half == 0 && lane == 0) {
        const float H0 = pw[w][0] + pw[w + 1][0];
        const float H1 = pw[w][1] + pw[w + 1][1];
        const float H2 = pw[w][2] + pw[w + 1][2];
        const float E0 = pw[w][3] + pw[w + 1][3];
        const float E1 = pw[w][4] + pw[w + 1][4];
        const float E2 = pw[w][5] + pw[w + 1][5];

        const float mx = fmaxf(H0, fmaxf(H1, H2));
        const float e0 = __expf(H0 - mx), e1 = __expf(H1 - mx), e2 = __expf(H2 - mx);
        const float inv = 1.0f / (e0 + e1 + e2);
        const float emb0 = e0 * inv, emb1 = e1 * inv, emb2 = e2 * inv;

        float ext[3];
        #pragma unroll
        for (int e = 0; e < 3; ++e) {
            const float vv = emb0 * U[e] + emb1 * U[3 + e] + emb2 * U[6 + e]
                           + E0   * V[e] + E1   * V[3 + e] + E2   * V[6 + e];
            ext[e] = fmaxf(vv, 0.f);
        }
        const float mx2 = fmaxf(ext[0], fmaxf(ext[1], ext[2]));
        const float f0 = __expf(ext[0] - mx2), f1 = __expf(ext[1] - mx2), f2 = __expf(ext[2] - mx2);
        const float inv2 = 1.0f / (f0 + f1 + f2);
        ge[gslot][0] = f0 * inv2; ge[gslot][1] = f1 * inv2; ge[gslot][2] = f2 * inv2;
    }

    __syncthreads();

    // ---- pair combine on thread 0 -----------------------------------------
    if (t == 0) {
        float tt[6];
        tt[0] = ge[0][0] * ge[1][0];
        tt[1] = ge[0][1] * ge[1][1];
        tt[2] = ge[0][2] * ge[1][2];
        tt[3] = ge[0][0] + ge[1][0];
        tt[4] = ge[0][1] + ge[1][1];
        tt[5] = ge[0][2] + ge[1][2];

        float hl[3];
        #pragma unroll
        for (int j = 0; j < 3; ++j) {
            float vv = b1[j];
            #pragma unroll
            for (int i = 0; i < 6; ++i) vv += tt[i] * W1[i * 3 + j];
            hl[j] = fmaxf(vv, 0.f);
        }

        const float l0 = b2[0] + hl[0] * W2[0] + hl[1] * W2[2] + hl[2] * W2[4];
        const float l1 = b2[1] + hl[0] * W2[1] + hl[1] * W2[3] + hl[2] * W2[5];
        const float mm = fmaxf(l0, l1);
        const float q0 = __expf(l0 - mm), q1 = __expf(l1 - mm);
        const float qi = 1.0f / (q0 + q1);
        out[(size_t)pair * 2    ] = q0 * qi;
        out[(size_t)pair * 2 + 1] = q1 * qi;
    }
}

extern "C" void kernel_launch(void* const* d_in, const int* in_sizes, int n_in,
                              void* d_out, int out_size, void* d_ws, size_t ws_size,
                              hipStream_t stream) {
    const float* x    = (const float*)d_in[0];
    const int*   esrc = (const int*)  d_in[1];
    const int*   edst = (const int*)  d_in[2];
    const float* extx = (const float*)d_in[3];
    const float* W    = (const float*)d_in[4];
    const float* M    = (const float*)d_in[5];
    const float* U    = (const float*)d_in[6];
    const float* V    = (const float*)d_in[7];
    const float* W1   = (const float*)d_in[8];
    const float* b1   = (const float*)d_in[9];
    const float* W2   = (const float*)d_in[10];
    const float* b2   = (const float*)d_in[11];
    float* out = (float*)d_out;

    dcnn_adj_kernel<<<NB, 256, 0, stream>>>(
        x, esrc, edst, extx, W, M, U, V, W1, b1, W2, b2, out);
}